// Round 4
// baseline (669.156 us; speedup 1.0000x reference)
//
#include <hip/hip_runtime.h>
#include <stdint.h>

typedef unsigned short u16;
typedef unsigned int u32;
typedef __attribute__((ext_vector_type(4))) u16 u16x4;
typedef __attribute__((ext_vector_type(8))) u16 u16x8;
typedef __attribute__((ext_vector_type(2))) u32 u32x2;
typedef __attribute__((ext_vector_type(8))) short bf16x8;
typedef __attribute__((ext_vector_type(4))) float f32x4;

#define DEVFN __device__ __forceinline__

DEVFN u16 f2bf(float f) {
  union { float f; u32 u; } x; x.f = f;
  u32 u = x.u;
  return (u16)((u + 0x7fffu + ((u >> 16) & 1u)) >> 16);
}

// ---------------- fp32 -> bf16 convert ----------------
__global__ void cvt_kernel(const float* __restrict__ in, u16* __restrict__ out, int n4) {
  const int stride = gridDim.x * blockDim.x;
  for (int i = blockIdx.x * blockDim.x + threadIdx.x; i < n4; i += stride) {
    float4 v = reinterpret_cast<const float4*>(in)[i];
    u16x4 o;
    o.x = f2bf(v.x); o.y = f2bf(v.y); o.z = f2bf(v.z); o.w = f2bf(v.w);
    reinterpret_cast<u16x4*>(out)[i] = o;
  }
}

// ---------------- padded bias table: pbp[h][i][j64] (pad = 0) ----------------
__global__ void pbp_kernel(const float* __restrict__ bt, const int* __restrict__ ri,
                           float* __restrict__ pbp) {
  const int h = blockIdx.x;
  for (int t = threadIdx.x; t < 4096; t += 256) {
    const int i = t >> 6, j = t & 63;
    float v = 0.f;
    if (i < 49 && j < 49) v = bt[ri[i * 49 + j] * 16 + h];
    pbp[h * 4096 + t] = v;
  }
}

// ---------------- padded mask: maskp[w][i][j64] (pad = -1e30) ----------------
__global__ void maskp_kernel(const float* __restrict__ mask, float* __restrict__ maskp) {
  const int w = blockIdx.x;
  for (int t = threadIdx.x; t < 4096; t += 256) {
    const int i = t >> 6, j = t & 63;
    float v = -1e30f;
    if (i < 49 && j < 49) v = mask[w * 2401 + i * 49 + j];
    maskp[w * 4096 + t] = v;
  }
}

// ---------------- bf16 GEMM: C = A @ Bt^T + bias ----------------
// blockIdx.x = n-tile (FAST: co-schedules all n-tiles of one A-panel -> A read ~once from HBM)
// blockIdx.y = m-tile
template <int MODE>
__global__ __launch_bounds__(256) void gemm_kernel(
    const u16* __restrict__ A, const u16* __restrict__ Bt,
    const float* __restrict__ bias, void* __restrict__ Out,
    int K, int ldo) {
  __shared__ u16 sA[128 * 64];
  __shared__ u16 sB[128 * 64];
  const int tid = threadIdx.x;
  const int lane = tid & 63;
  const int wid = tid >> 6;
  const int m0 = blockIdx.y * 128;
  const int n0 = blockIdx.x * 128;
  const int wr = wid >> 1, wc = wid & 1;
  const int l15 = lane & 15, lg = lane >> 4;

  f32x4 acc[4][4] = {};

  const int sr = lane >> 3;  // row within 8-row stage group
  const int ss = lane & 7;   // 16B slot within 128B row

  for (int kk = 0; kk < K; kk += 64) {
    __syncthreads();
#pragma unroll
    for (int i = 0; i < 4; ++i) {
      const int r = wid * 32 + i * 8 + sr;
      const int srcs = ss ^ (r & 7);  // pre-swizzled source -> linear LDS dest
      const u16* ga = A + (size_t)(m0 + r) * K + kk + srcs * 8;
      const u16* gb = Bt + (size_t)(n0 + r) * K + kk + srcs * 8;
      __builtin_amdgcn_global_load_lds(
          (const __attribute__((address_space(1))) void*)ga,
          (__attribute__((address_space(3))) void*)(sA + (wid * 32 + i * 8) * 64), 16, 0, 0);
      __builtin_amdgcn_global_load_lds(
          (const __attribute__((address_space(1))) void*)gb,
          (__attribute__((address_space(3))) void*)(sB + (wid * 32 + i * 8) * 64), 16, 0, 0);
    }
    __syncthreads();
#pragma unroll
    for (int ks = 0; ks < 2; ++ks) {
      bf16x8 af[4], bfr[4];
#pragma unroll
      for (int mi = 0; mi < 4; ++mi) {
        const int m = wr * 64 + mi * 16 + l15;
        const int slot = (ks * 4 + lg) ^ (m & 7);
        af[mi] = *reinterpret_cast<const bf16x8*>(sA + m * 64 + slot * 8);
      }
#pragma unroll
      for (int ni = 0; ni < 4; ++ni) {
        const int n = wc * 64 + ni * 16 + l15;
        const int slot = (ks * 4 + lg) ^ (n & 7);
        bfr[ni] = *reinterpret_cast<const bf16x8*>(sB + n * 64 + slot * 8);
      }
#pragma unroll
      for (int mi = 0; mi < 4; ++mi)
#pragma unroll
        for (int ni = 0; ni < 4; ++ni)
          acc[mi][ni] = __builtin_amdgcn_mfma_f32_16x16x32_bf16(af[mi], bfr[ni], acc[mi][ni], 0, 0, 0);
    }
  }

#pragma unroll
  for (int mi = 0; mi < 4; ++mi) {
#pragma unroll
    for (int ni = 0; ni < 4; ++ni) {
      const int col = n0 + wc * 64 + ni * 16 + l15;
      const float bv = bias[col];
      const int rbase = m0 + wr * 64 + mi * 16 + lg * 4;
#pragma unroll
      for (int r = 0; r < 4; ++r) {
        const float v = acc[mi][ni][r] + bv;
        if (MODE == 0) {
          ((u16*)Out)[(size_t)(rbase + r) * ldo + col] = f2bf(v);
        } else {
          ((float*)Out)[(size_t)(rbase + r) * ldo + col] = v;
        }
      }
    }
  }
}

// ---------------- attention: one wave per (window, head), 4 heads/block ----------------
// Swapped QK^T (S^T = K@Q^T) makes softmax j-axis lane-local; V stored pi-permuted in
// LDS so the PV A-fragment is the lane's own packed P values: no barriers, no sP.
// pi(j) = (kt>>1)*32 + lgj*8 + (kt&1)*4 + r  for j = kt*16 + lgj*4 + r.
__global__ __launch_bounds__(256) void attn_kernel(
    const u16* __restrict__ qkv, const float* __restrict__ pbp,
    const float* __restrict__ maskp, u16* __restrict__ attn_out) {
  const int w = threadIdx.x >> 6;
  const int lane = threadIdx.x & 63;
  const int b = blockIdx.x >> 2;
  const int h = ((blockIdx.x & 3) << 2) | w;
  const int l15 = lane & 15, lg = lane >> 4;

  __shared__ u16 sVT[4][32][72];  // per-wave private slab: V^T, pi-permuted columns
  u16 (*vt)[72] = sVT[w];

  // zero own slab (padded columns must be 0; no barrier: wave-private)
  for (int i = lane; i < 1152; i += 64) ((u32*)vt)[i] = 0;

  const size_t rowbase = (size_t)b * (49 * 1536) + h * 32;

  // V scatter: sVT[d][pi(n)] = V[n][d]
  for (int c = lane; c < 196; c += 64) {
    const int n = c >> 2, dg = c & 3;
    u16x8 vv = *reinterpret_cast<const u16x8*>(qkv + rowbase + (size_t)n * 1536 + 1024 + dg * 8);
    const int pin = ((n >> 5) << 5) | ((((n >> 2) & 3)) << 3) | (((n >> 4) & 1) << 2) | (n & 3);
#pragma unroll
    for (int j = 0; j < 8; ++j) vt[dg * 8 + j][pin] = vv[j];
  }

  // Q,K fragments straight from global (rows >=49 clamped; padding handled by maskp)
  bf16x8 aq[4], bk[4];
#pragma unroll
  for (int t = 0; t < 4; ++t) {
    const int i = t * 16 + l15;
    const int r = i < 49 ? i : 48;
    const size_t ro = rowbase + (size_t)r * 1536 + lg * 8;
    aq[t] = *reinterpret_cast<const bf16x8*>(qkv + ro);
    bk[t] = *reinterpret_cast<const bf16x8*>(qkv + ro + 512);
  }

  // V fragments (after scatter; same-wave lgkmcnt ordering)
  bf16x8 bv[2][2];
#pragma unroll
  for (int ni = 0; ni < 2; ++ni)
#pragma unroll
    for (int ks = 0; ks < 2; ++ks)
      bv[ni][ks] = *reinterpret_cast<const bf16x8*>(&vt[ni * 16 + l15][ks * 32 + lg * 8]);

  const float scale = 0.17677669529663687f;
  const float* pbh = pbp + (h << 12);
  const float* mw = maskp + ((size_t)(b & 63) << 12);
  const size_t obase = (size_t)b * 49 * 512 + h * 32;

#pragma unroll
  for (int qt = 0; qt < 4; ++qt) {
    // S^T tile: lane holds S[q=qt*16+l15][j=kt*16+lg*4+r]
    f32x4 sT[4] = {};
#pragma unroll
    for (int kt = 0; kt < 4; ++kt)
      sT[kt] = __builtin_amdgcn_mfma_f32_16x16x32_bf16(bk[kt], aq[qt], sT[kt], 0, 0, 0);

    const int i = qt * 16 + l15;
    const float* pr = pbh + i * 64 + lg * 4;
    const float* mr = mw + i * 64 + lg * 4;
    float v[4][4];
    float mx = -3e38f;
#pragma unroll
    for (int kt = 0; kt < 4; ++kt) {
      f32x4 pv = *reinterpret_cast<const f32x4*>(pr + kt * 16);
      f32x4 mv = *reinterpret_cast<const f32x4*>(mr + kt * 16);
#pragma unroll
      for (int r = 0; r < 4; ++r) {
        const float val = fmaf(sT[kt][r], scale, pv[r] + mv[r]);
        v[kt][r] = val;
        mx = fmaxf(mx, val);
      }
    }
    mx = fmaxf(mx, __shfl_xor(mx, 16));
    mx = fmaxf(mx, __shfl_xor(mx, 32));
    float sum = 0.f;
#pragma unroll
    for (int kt = 0; kt < 4; ++kt)
#pragma unroll
      for (int r = 0; r < 4; ++r) {
        const float e = __expf(v[kt][r] - mx);
        v[kt][r] = e;
        sum += e;
      }
    sum += __shfl_xor(sum, 16);
    sum += __shfl_xor(sum, 32);
    const float rinv = 1.0f / sum;

    // pack normalized P into PV A-fragments (pi-order: lane-local, no shuffles)
    bf16x8 ap[2];
#pragma unroll
    for (int ks = 0; ks < 2; ++ks) {
      u32 w0 = (u32)f2bf(v[2 * ks][0] * rinv) | ((u32)f2bf(v[2 * ks][1] * rinv) << 16);
      u32 w1 = (u32)f2bf(v[2 * ks][2] * rinv) | ((u32)f2bf(v[2 * ks][3] * rinv) << 16);
      u32 w2 = (u32)f2bf(v[2 * ks + 1][0] * rinv) | ((u32)f2bf(v[2 * ks + 1][1] * rinv) << 16);
      u32 w3 = (u32)f2bf(v[2 * ks + 1][2] * rinv) | ((u32)f2bf(v[2 * ks + 1][3] * rinv) << 16);
      union { u32 u[4]; bf16x8 b; } pk;
      pk.u[0] = w0; pk.u[1] = w1; pk.u[2] = w2; pk.u[3] = w3;
      ap[ks] = pk.b;
    }

    // O tile for this q-tile
    f32x4 o[2] = {};
#pragma unroll
    for (int ks = 0; ks < 2; ++ks)
#pragma unroll
      for (int ni = 0; ni < 2; ++ni)
        o[ni] = __builtin_amdgcn_mfma_f32_16x16x32_bf16(ap[ks], bv[ni][ks], o[ni], 0, 0, 0);

#pragma unroll
    for (int r = 0; r < 4; ++r) {
      const int iq = qt * 16 + lg * 4 + r;
      if (iq < 49) {
#pragma unroll
        for (int ni = 0; ni < 2; ++ni)
          attn_out[obase + (size_t)iq * 512 + ni * 16 + l15] = f2bf(o[ni][r]);
      }
    }
  }
}

extern "C" void kernel_launch(void* const* d_in, const int* in_sizes, int n_in,
                              void* d_out, int out_size, void* d_ws, size_t ws_size,
                              hipStream_t stream) {
  (void)in_sizes; (void)n_in; (void)out_size; (void)ws_size;
  const float* x          = (const float*)d_in[0];
  const float* w_qkv      = (const float*)d_in[1];
  const float* b_qkv      = (const float*)d_in[2];
  const float* w_proj     = (const float*)d_in[3];
  const float* b_proj     = (const float*)d_in[4];
  const float* bias_table = (const float*)d_in[5];
  const int*   rel_index  = (const int*)d_in[6];
  const float* mask       = (const float*)d_in[7];

  u16* ws     = (u16*)d_ws;
  u16* xbf    = ws;                    // 51,380,224 elems (reused as attn_out)
  u16* qkv    = ws + 51380224;         // 154,140,672 elems
  u16* wqkvb  = qkv + 154140672;       // 786,432 elems
  u16* wprojb = wqkvb + 786432;        // 262,144 elems
  float* pbp  = (float*)(wprojb + 262144);  // 16*4096 floats
  float* mkp  = pbp + 16 * 4096;            // 64*4096 floats

  cvt_kernel<<<2048, 256, 0, stream>>>(x, xbf, 51380224 / 4);
  cvt_kernel<<<192, 256, 0, stream>>>(w_qkv, wqkvb, 786432 / 4);
  cvt_kernel<<<64, 256, 0, stream>>>(w_proj, wprojb, 262144 / 4);
  pbp_kernel<<<16, 256, 0, stream>>>(bias_table, rel_index, pbp);
  maskp_kernel<<<64, 256, 0, stream>>>(mask, mkp);

  gemm_kernel<0><<<dim3(12, 784), 256, 0, stream>>>(xbf, wqkvb, b_qkv, qkv, 512, 1536);
  attn_kernel<<<8192, 256, 0, stream>>>(qkv, pbp, mkp, xbf);
  gemm_kernel<1><<<dim3(4, 784), 256, 0, stream>>>(xbf, wprojb, b_proj, d_out, 512, 512);
}

// Round 5
// 628.467 us; speedup vs baseline: 1.0647x; 1.0647x over previous
//
#include <hip/hip_runtime.h>
#include <stdint.h>

typedef unsigned short u16;
typedef unsigned int u32;
typedef __attribute__((ext_vector_type(4))) u16 u16x4;
typedef __attribute__((ext_vector_type(8))) u16 u16x8;
typedef __attribute__((ext_vector_type(2))) u32 u32x2;
typedef __attribute__((ext_vector_type(8))) short bf16x8;
typedef __attribute__((ext_vector_type(4))) float f32x4;

#define DEVFN __device__ __forceinline__

DEVFN u16 f2bf(float f) {
  union { float f; u32 u; } x; x.f = f;
  u32 u = x.u;
  return (u16)((u + 0x7fffu + ((u >> 16) & 1u)) >> 16);
}

// ---------------- fp32 -> bf16 convert ----------------
__global__ void cvt_kernel(const float* __restrict__ in, u16* __restrict__ out, int n4) {
  const int stride = gridDim.x * blockDim.x;
  for (int i = blockIdx.x * blockDim.x + threadIdx.x; i < n4; i += stride) {
    float4 v = reinterpret_cast<const float4*>(in)[i];
    u16x4 o;
    o.x = f2bf(v.x); o.y = f2bf(v.y); o.z = f2bf(v.z); o.w = f2bf(v.w);
    reinterpret_cast<u16x4*>(out)[i] = o;
  }
}

// ---------------- padded bias table: pbp[h][i][j64] (pad = 0) ----------------
__global__ void pbp_kernel(const float* __restrict__ bt, const int* __restrict__ ri,
                           float* __restrict__ pbp) {
  const int h = blockIdx.x;
  for (int t = threadIdx.x; t < 4096; t += 256) {
    const int i = t >> 6, j = t & 63;
    float v = 0.f;
    if (i < 49 && j < 49) v = bt[ri[i * 49 + j] * 16 + h];
    pbp[h * 4096 + t] = v;
  }
}

// ---------------- padded mask: maskp[w][i][j64] (pad = -1e30) ----------------
__global__ void maskp_kernel(const float* __restrict__ mask, float* __restrict__ maskp) {
  const int w = blockIdx.x;
  for (int t = threadIdx.x; t < 4096; t += 256) {
    const int i = t >> 6, j = t & 63;
    float v = -1e30f;
    if (i < 49 && j < 49) v = mask[w * 2401 + i * 49 + j];
    maskp[w * 4096 + t] = v;
  }
}

// ---------------- bf16 GEMM: C = A @ Bt^T + bias, K=512 fixed ----------------
// Double-buffered LDS + counted vmcnt pipeline (raw s_barrier, never vmcnt(0) in
// the steady loop). 1-D grid, XCD-chunked: xcd=bid&7 owns MCHUNK contiguous
// m-tiles x all n-tiles -> each A-panel read by exactly one XCD's L2.
#define WAIT_LGKM0 asm volatile("s_waitcnt lgkmcnt(0)" ::: "memory")
#define WAIT_VM8   asm volatile("s_waitcnt vmcnt(8)" ::: "memory")
#define WAIT_VM0   asm volatile("s_waitcnt vmcnt(0)" ::: "memory")
#define SCHEDB     __builtin_amdgcn_sched_barrier(0)
#define BARRIER    __builtin_amdgcn_s_barrier()

template <int MODE, int NTILES, int MCHUNK>
__global__ __launch_bounds__(256) void gemm_kernel(
    const u16* __restrict__ A, const u16* __restrict__ Bt,
    const float* __restrict__ bias, void* __restrict__ Out, int ldo) {
  __shared__ u16 sA[2][128 * 64];
  __shared__ u16 sB[2][128 * 64];
  const int tid = threadIdx.x;
  const int lane = tid & 63;
  const int wid = tid >> 6;
  const int bid = blockIdx.x;
  const int xcd = bid & 7;
  const int slot = bid >> 3;
  const int m0 = (xcd * MCHUNK + slot / NTILES) * 128;
  const int n0 = (slot % NTILES) * 128;
  const int wr = wid >> 1, wc = wid & 1;
  const int l15 = lane & 15, lg = lane >> 4;
  const int sr = lane >> 3;  // row within 8-row stage group
  const int ss = lane & 7;   // 16B slot within 128B row

#define STAGE(kt, bufi)                                                        \
  {                                                                            \
    _Pragma("unroll") for (int i = 0; i < 4; ++i) {                            \
      const int r = wid * 32 + i * 8 + sr;                                     \
      const int srcs = ss ^ (r & 7);                                           \
      const u16* ga = A + (size_t)(m0 + r) * 512 + (kt) * 64 + srcs * 8;       \
      const u16* gb = Bt + (size_t)(n0 + r) * 512 + (kt) * 64 + srcs * 8;      \
      __builtin_amdgcn_global_load_lds(                                        \
          (const __attribute__((address_space(1))) void*)ga,                   \
          (__attribute__((address_space(3))) void*)(sA[bufi] +                 \
                                                    (wid * 32 + i * 8) * 64),  \
          16, 0, 0);                                                           \
      __builtin_amdgcn_global_load_lds(                                        \
          (const __attribute__((address_space(1))) void*)gb,                   \
          (__attribute__((address_space(3))) void*)(sB[bufi] +                 \
                                                    (wid * 32 + i * 8) * 64),  \
          16, 0, 0);                                                           \
    }                                                                          \
  }

  f32x4 acc[4][4] = {};

  STAGE(0, 0);
  STAGE(1, 1);
  WAIT_VM8;      // tile 0 landed (own 8 of tile1 may fly)
  BARRIER;       // all waves' tile 0 landed
  SCHEDB;

#pragma unroll
  for (int t = 0; t < 8; ++t) {
    const int cur = t & 1;
    // ---- all fragments of tile t into regs ----
    bf16x8 af[2][4], bfr[2][4];
#pragma unroll
    for (int ks = 0; ks < 2; ++ks) {
#pragma unroll
      for (int mi = 0; mi < 4; ++mi) {
        const int m = wr * 64 + mi * 16 + l15;
        const int slotm = (ks * 4 + lg) ^ (m & 7);
        af[ks][mi] = *reinterpret_cast<const bf16x8*>(sA[cur] + m * 64 + slotm * 8);
      }
#pragma unroll
      for (int ni = 0; ni < 4; ++ni) {
        const int n = wc * 64 + ni * 16 + l15;
        const int slotn = (ks * 4 + lg) ^ (n & 7);
        bfr[ks][ni] = *reinterpret_cast<const bf16x8*>(sB[cur] + n * 64 + slotn * 8);
      }
    }
    WAIT_LGKM0;  // frags in regs; this wave done reading buf[cur]
    SCHEDB;
    BARRIER;     // ALL waves done reading buf[cur] -> safe to overwrite
    SCHEDB;
    if (t < 6) STAGE(t + 2, cur);  // async into just-freed buffer
    __builtin_amdgcn_s_setprio(1);
#pragma unroll
    for (int ks = 0; ks < 2; ++ks)
#pragma unroll
      for (int mi = 0; mi < 4; ++mi)
#pragma unroll
        for (int ni = 0; ni < 4; ++ni)
          acc[mi][ni] = __builtin_amdgcn_mfma_f32_16x16x32_bf16(af[ks][mi], bfr[ks][ni], acc[mi][ni], 0, 0, 0);
    __builtin_amdgcn_s_setprio(0);
    SCHEDB;
    if (t < 6) {
      WAIT_VM8;  // tile t+1 landed (only t+2's 8 may remain)
    } else if (t == 6) {
      WAIT_VM0;  // last prefetch (tile 7) landed
    }
    if (t < 7) {
      BARRIER;   // all waves' tile t+1 landed
      SCHEDB;
    }
  }
#undef STAGE

#pragma unroll
  for (int mi = 0; mi < 4; ++mi) {
#pragma unroll
    for (int ni = 0; ni < 4; ++ni) {
      const int col = n0 + wc * 64 + ni * 16 + l15;
      const float bv = bias[col];
      const int rbase = m0 + wr * 64 + mi * 16 + lg * 4;
#pragma unroll
      for (int r = 0; r < 4; ++r) {
        const float v = acc[mi][ni][r] + bv;
        if (MODE == 0) {
          ((u16*)Out)[(size_t)(rbase + r) * ldo + col] = f2bf(v);
        } else {
          ((float*)Out)[(size_t)(rbase + r) * ldo + col] = v;
        }
      }
    }
  }
}

// ---------------- attention: one wave per (window, head), 4 heads/block ----------------
// Swapped QK^T (S^T = K@Q^T) makes softmax j-axis lane-local; V stored pi-permuted in
// LDS so the PV A-fragment is the lane's own packed P values: no barriers, no sP.
// pi(j) = (kt>>1)*32 + lgj*8 + (kt&1)*4 + r  for j = kt*16 + lgj*4 + r.
__global__ __launch_bounds__(256) void attn_kernel(
    const u16* __restrict__ qkv, const float* __restrict__ pbp,
    const float* __restrict__ maskp, u16* __restrict__ attn_out) {
  const int w = threadIdx.x >> 6;
  const int lane = threadIdx.x & 63;
  const int b = blockIdx.x >> 2;
  const int h = ((blockIdx.x & 3) << 2) | w;
  const int l15 = lane & 15, lg = lane >> 4;

  __shared__ u16 sVT[4][32][72];  // per-wave private slab: V^T, pi-permuted columns
  u16 (*vt)[72] = sVT[w];

  // zero own slab (padded columns must be 0; no barrier: wave-private)
  for (int i = lane; i < 1152; i += 64) ((u32*)vt)[i] = 0;

  const size_t rowbase = (size_t)b * (49 * 1536) + h * 32;

  // V scatter: sVT[d][pi(n)] = V[n][d]
  for (int c = lane; c < 196; c += 64) {
    const int n = c >> 2, dg = c & 3;
    u16x8 vv = *reinterpret_cast<const u16x8*>(qkv + rowbase + (size_t)n * 1536 + 1024 + dg * 8);
    const int pin = ((n >> 5) << 5) | ((((n >> 2) & 3)) << 3) | (((n >> 4) & 1) << 2) | (n & 3);
#pragma unroll
    for (int j = 0; j < 8; ++j) vt[dg * 8 + j][pin] = vv[j];
  }

  // Q,K fragments straight from global (rows >=49 clamped; padding handled by maskp)
  bf16x8 aq[4], bk[4];
#pragma unroll
  for (int t = 0; t < 4; ++t) {
    const int i = t * 16 + l15;
    const int r = i < 49 ? i : 48;
    const size_t ro = rowbase + (size_t)r * 1536 + lg * 8;
    aq[t] = *reinterpret_cast<const bf16x8*>(qkv + ro);
    bk[t] = *reinterpret_cast<const bf16x8*>(qkv + ro + 512);
  }

  // V fragments (after scatter; same-wave lgkmcnt ordering)
  bf16x8 bv[2][2];
#pragma unroll
  for (int ni = 0; ni < 2; ++ni)
#pragma unroll
    for (int ks = 0; ks < 2; ++ks)
      bv[ni][ks] = *reinterpret_cast<const bf16x8*>(&vt[ni * 16 + l15][ks * 32 + lg * 8]);

  const float scale = 0.17677669529663687f;
  const float* pbh = pbp + (h << 12);
  const float* mw = maskp + ((size_t)(b & 63) << 12);
  const size_t obase = (size_t)b * 49 * 512 + h * 32;

#pragma unroll
  for (int qt = 0; qt < 4; ++qt) {
    // S^T tile: lane holds S[q=qt*16+l15][j=kt*16+lg*4+r]
    f32x4 sT[4] = {};
#pragma unroll
    for (int kt = 0; kt < 4; ++kt)
      sT[kt] = __builtin_amdgcn_mfma_f32_16x16x32_bf16(bk[kt], aq[qt], sT[kt], 0, 0, 0);

    const int i = qt * 16 + l15;
    const float* pr = pbh + i * 64 + lg * 4;
    const float* mr = mw + i * 64 + lg * 4;
    float v[4][4];
    float mx = -3e38f;
#pragma unroll
    for (int kt = 0; kt < 4; ++kt) {
      f32x4 pv = *reinterpret_cast<const f32x4*>(pr + kt * 16);
      f32x4 mv = *reinterpret_cast<const f32x4*>(mr + kt * 16);
#pragma unroll
      for (int r = 0; r < 4; ++r) {
        const float val = fmaf(sT[kt][r], scale, pv[r] + mv[r]);
        v[kt][r] = val;
        mx = fmaxf(mx, val);
      }
    }
    mx = fmaxf(mx, __shfl_xor(mx, 16));
    mx = fmaxf(mx, __shfl_xor(mx, 32));
    float sum = 0.f;
#pragma unroll
    for (int kt = 0; kt < 4; ++kt)
#pragma unroll
      for (int r = 0; r < 4; ++r) {
        const float e = __expf(v[kt][r] - mx);
        v[kt][r] = e;
        sum += e;
      }
    sum += __shfl_xor(sum, 16);
    sum += __shfl_xor(sum, 32);
    const float rinv = 1.0f / sum;

    // pack normalized P into PV A-fragments (pi-order: lane-local, no shuffles)
    bf16x8 ap[2];
#pragma unroll
    for (int ks = 0; ks < 2; ++ks) {
      u32 w0 = (u32)f2bf(v[2 * ks][0] * rinv) | ((u32)f2bf(v[2 * ks][1] * rinv) << 16);
      u32 w1 = (u32)f2bf(v[2 * ks][2] * rinv) | ((u32)f2bf(v[2 * ks][3] * rinv) << 16);
      u32 w2 = (u32)f2bf(v[2 * ks + 1][0] * rinv) | ((u32)f2bf(v[2 * ks + 1][1] * rinv) << 16);
      u32 w3 = (u32)f2bf(v[2 * ks + 1][2] * rinv) | ((u32)f2bf(v[2 * ks + 1][3] * rinv) << 16);
      union { u32 u[4]; bf16x8 b; } pk;
      pk.u[0] = w0; pk.u[1] = w1; pk.u[2] = w2; pk.u[3] = w3;
      ap[ks] = pk.b;
    }

    // O tile for this q-tile
    f32x4 o[2] = {};
#pragma unroll
    for (int ks = 0; ks < 2; ++ks)
#pragma unroll
      for (int ni = 0; ni < 2; ++ni)
        o[ni] = __builtin_amdgcn_mfma_f32_16x16x32_bf16(ap[ks], bv[ni][ks], o[ni], 0, 0, 0);

#pragma unroll
    for (int r = 0; r < 4; ++r) {
      const int iq = qt * 16 + lg * 4 + r;
      if (iq < 49) {
#pragma unroll
        for (int ni = 0; ni < 2; ++ni)
          attn_out[obase + (size_t)iq * 512 + ni * 16 + l15] = f2bf(o[ni][r]);
      }
    }
  }
}

extern "C" void kernel_launch(void* const* d_in, const int* in_sizes, int n_in,
                              void* d_out, int out_size, void* d_ws, size_t ws_size,
                              hipStream_t stream) {
  (void)in_sizes; (void)n_in; (void)out_size; (void)ws_size;
  const float* x          = (const float*)d_in[0];
  const float* w_qkv      = (const float*)d_in[1];
  const float* b_qkv      = (const float*)d_in[2];
  const float* w_proj     = (const float*)d_in[3];
  const float* b_proj     = (const float*)d_in[4];
  const float* bias_table = (const float*)d_in[5];
  const int*   rel_index  = (const int*)d_in[6];
  const float* mask       = (const float*)d_in[7];

  u16* ws     = (u16*)d_ws;
  u16* xbf    = ws;                    // 51,380,224 elems (reused as attn_out)
  u16* qkv    = ws + 51380224;         // 154,140,672 elems
  u16* wqkvb  = qkv + 154140672;       // 786,432 elems
  u16* wprojb = wqkvb + 786432;        // 262,144 elems
  float* pbp  = (float*)(wprojb + 262144);  // 16*4096 floats
  float* mkp  = pbp + 16 * 4096;            // 64*4096 floats

  cvt_kernel<<<2048, 256, 0, stream>>>(x, xbf, 51380224 / 4);
  cvt_kernel<<<192, 256, 0, stream>>>(w_qkv, wqkvb, 786432 / 4);
  cvt_kernel<<<64, 256, 0, stream>>>(w_proj, wprojb, 262144 / 4);
  pbp_kernel<<<16, 256, 0, stream>>>(bias_table, rel_index, pbp);
  maskp_kernel<<<64, 256, 0, stream>>>(mask, mkp);

  // 784 m-tiles = 8 XCDs * 98; GEMM1: 12 n-tiles, GEMM2: 4 n-tiles
  gemm_kernel<0, 12, 98><<<9408, 256, 0, stream>>>(xbf, wqkvb, b_qkv, qkv, 1536);
  attn_kernel<<<8192, 256, 0, stream>>>(qkv, pbp, mkp, xbf);
  gemm_kernel<1, 4, 98><<<3136, 256, 0, stream>>>(xbf, wprojb, b_proj, d_out, 512);
}

// Round 6
// 568.287 us; speedup vs baseline: 1.1775x; 1.1059x over previous
//
#include <hip/hip_runtime.h>
#include <stdint.h>

typedef unsigned short u16;
typedef unsigned int u32;
typedef __attribute__((ext_vector_type(4))) u16 u16x4;
typedef __attribute__((ext_vector_type(8))) u16 u16x8;
typedef __attribute__((ext_vector_type(2))) u32 u32x2;
typedef __attribute__((ext_vector_type(8))) short bf16x8;
typedef __attribute__((ext_vector_type(4))) float f32x4;

#define DEVFN __device__ __forceinline__

DEVFN u16 f2bf(float f) {
  union { float f; u32 u; } x; x.f = f;
  u32 u = x.u;
  return (u16)((u + 0x7fffu + ((u >> 16) & 1u)) >> 16);
}

// ---------------- fp32 -> bf16 convert ----------------
__global__ void cvt_kernel(const float* __restrict__ in, u16* __restrict__ out, int n4) {
  const int stride = gridDim.x * blockDim.x;
  for (int i = blockIdx.x * blockDim.x + threadIdx.x; i < n4; i += stride) {
    float4 v = reinterpret_cast<const float4*>(in)[i];
    u16x4 o;
    o.x = f2bf(v.x); o.y = f2bf(v.y); o.z = f2bf(v.z); o.w = f2bf(v.w);
    reinterpret_cast<u16x4*>(out)[i] = o;
  }
}

// ---------------- padded bias table: pbp[h][i][j64] (pad = 0) ----------------
__global__ void pbp_kernel(const float* __restrict__ bt, const int* __restrict__ ri,
                           float* __restrict__ pbp) {
  const int h = blockIdx.x;
  for (int t = threadIdx.x; t < 4096; t += 256) {
    const int i = t >> 6, j = t & 63;
    float v = 0.f;
    if (i < 49 && j < 49) v = bt[ri[i * 49 + j] * 16 + h];
    pbp[h * 4096 + t] = v;
  }
}

// ---------------- padded mask: maskp[w][i][j64] (pad = -1e30) ----------------
__global__ void maskp_kernel(const float* __restrict__ mask, float* __restrict__ maskp) {
  const int w = blockIdx.x;
  for (int t = threadIdx.x; t < 4096; t += 256) {
    const int i = t >> 6, j = t & 63;
    float v = -1e30f;
    if (i < 49 && j < 49) v = mask[w * 2401 + i * 49 + j];
    maskp[w * 4096 + t] = v;
  }
}

// ---------------- bf16 GEMM: C = A @ Bt^T + bias, K=512 fixed ----------------
// 256x256 tile, 8 waves (2M x 4N), BK=64, double-buffered 128 KB LDS,
// 4-phase quadrant interleave per K-tile, 2-K-tiles-ahead prefetch with
// counted vmcnt(8). XCD-chunked 1-D grid (bid&7 = XCD owns MCHUNK m-tiles).
#define WAIT_LGKM0 asm volatile("s_waitcnt lgkmcnt(0)" ::: "memory")
#define WAIT_VM8   asm volatile("s_waitcnt vmcnt(8)" ::: "memory")
#define WAIT_VM0   asm volatile("s_waitcnt vmcnt(0)" ::: "memory")
#define SCHEDB     __builtin_amdgcn_sched_barrier(0)
#define BARRIER    __builtin_amdgcn_s_barrier()
#define MFMA(a, b, c) __builtin_amdgcn_mfma_f32_16x16x32_bf16(a, b, c, 0, 0, 0)

template <int MODE, int NTILES, int MCHUNK>
__global__ __launch_bounds__(512) void gemm_kernel(
    const u16* __restrict__ A, const u16* __restrict__ Bt,
    const float* __restrict__ bias, void* __restrict__ Out, int ldo) {
  extern __shared__ u16 smem[];  // [buf0 A |buf0 B |buf1 A |buf1 B] x 16384 u16
  const int tid = threadIdx.x;
  const int lane = tid & 63;
  const int wid = tid >> 6;
  const int bid = blockIdx.x;
  const int xcd = bid & 7;
  const int slot = bid >> 3;
  const int m0 = (xcd * MCHUNK + slot / NTILES) * 256;
  const int n0 = (slot % NTILES) * 256;
  const int wr = wid >> 2, wc = wid & 3;  // wave -> (2M x 4N) sub-grid
  const int l15 = lane & 15, lg = lane >> 4;
  const int rg0 = tid >> 3;  // staging row within 64-row round
  const int sl0 = tid & 7;   // staging 16B slot within 128B row

  f32x4 acc[8][4] = {};

  u16* const sA0 = smem;
  u16* const sB0 = smem + 16384;
  u16* const sA1 = smem + 32768;
  u16* const sB1 = smem + 49152;

  // Per K-tile: A 256x64 (4 rounds of 512x16B) + B 256x64 -> 8 loads/thread.
  // Linear LDS dest (wave-uniform base + lane*16 by HW); source k-chunk
  // pre-swizzled by row&7 so ds_read at slot^(row&7) is conflict-free.
#define STAGE(kt_, sa_, sb_)                                                   \
  {                                                                            \
    _Pragma("unroll") for (int i = 0; i < 4; ++i) {                            \
      const int rg = i * 64 + rg0;                                             \
      const int kc = sl0 ^ (rg & 7);                                           \
      const u16* ga = A + (size_t)(m0 + rg) * 512 + (kt_) * 64 + kc * 8;       \
      __builtin_amdgcn_global_load_lds(                                        \
          (const __attribute__((address_space(1))) void*)ga,                   \
          (__attribute__((address_space(3))) void*)((sa_) + i * 4096 + wid * 512), \
          16, 0, 0);                                                           \
    }                                                                          \
    _Pragma("unroll") for (int i = 0; i < 4; ++i) {                            \
      const int rg = i * 64 + rg0;                                             \
      const int kc = sl0 ^ (rg & 7);                                           \
      const u16* gb = Bt + (size_t)(n0 + rg) * 512 + (kt_) * 64 + kc * 8;      \
      __builtin_amdgcn_global_load_lds(                                        \
          (const __attribute__((address_space(1))) void*)gb,                   \
          (__attribute__((address_space(3))) void*)((sb_) + i * 4096 + wid * 512), \
          16, 0, 0);                                                           \
    }                                                                          \
  }

#define RDA(dst, sa_, mi, ks)                                                  \
  {                                                                            \
    const int row_ = wr * 128 + (mi) * 16 + l15;                               \
    dst = *reinterpret_cast<const bf16x8*>(                                    \
        (sa_) + row_ * 64 + ((((ks) * 4 + lg) ^ (row_ & 7)) << 3));            \
  }
#define RDB(dst, sb_, ni, ks)                                                  \
  {                                                                            \
    const int row_ = wc * 64 + (ni) * 16 + l15;                                \
    dst = *reinterpret_cast<const bf16x8*>(                                    \
        (sb_) + row_ * 64 + ((((ks) * 4 + lg) ^ (row_ & 7)) << 3));            \
  }

  STAGE(0, sA0, sB0);
  STAGE(1, sA1, sB1);
  WAIT_VM8; SCHEDB;  // K-tile 0 landed (own 8 of tile 1 may still fly)
  BARRIER; SCHEDB;   // all waves' tile 0 landed

#pragma unroll
  for (int kt = 0; kt < 8; ++kt) {
    u16* const sa = (kt & 1) ? sA1 : sA0;
    u16* const sb = (kt & 1) ? sB1 : sB0;
    bf16x8 a0[4][2], a1[4][2], b0[2][2], b1[2][2];

    // ---- phase 0: A-half0 + B-half0 -> quadrant (M0,N0) ----
#pragma unroll
    for (int mi = 0; mi < 4; ++mi) { RDA(a0[mi][0], sa, mi, 0); RDA(a0[mi][1], sa, mi, 1); }
#pragma unroll
    for (int ni = 0; ni < 2; ++ni) { RDB(b0[ni][0], sb, ni, 0); RDB(b0[ni][1], sb, ni, 1); }
    WAIT_LGKM0; SCHEDB;
    __builtin_amdgcn_s_setprio(1);
#pragma unroll
    for (int mi = 0; mi < 4; ++mi)
#pragma unroll
      for (int ni = 0; ni < 2; ++ni)
#pragma unroll
        for (int ks = 0; ks < 2; ++ks)
          acc[mi][ni] = MFMA(a0[mi][ks], b0[ni][ks], acc[mi][ni]);
    __builtin_amdgcn_s_setprio(0); SCHEDB;

    // ---- phase 1: B-half1 -> quadrant (M0,N1) ----
#pragma unroll
    for (int ni = 0; ni < 2; ++ni) { RDB(b1[ni][0], sb, ni + 2, 0); RDB(b1[ni][1], sb, ni + 2, 1); }
    WAIT_LGKM0; SCHEDB;
    __builtin_amdgcn_s_setprio(1);
#pragma unroll
    for (int mi = 0; mi < 4; ++mi)
#pragma unroll
      for (int ni = 0; ni < 2; ++ni)
#pragma unroll
        for (int ks = 0; ks < 2; ++ks)
          acc[mi][ni + 2] = MFMA(a0[mi][ks], b1[ni][ks], acc[mi][ni + 2]);
    __builtin_amdgcn_s_setprio(0); SCHEDB;

    // ---- phase 2: A-half1 -> quadrant (M1,N1) ----
#pragma unroll
    for (int mi = 0; mi < 4; ++mi) { RDA(a1[mi][0], sa, mi + 4, 0); RDA(a1[mi][1], sa, mi + 4, 1); }
    WAIT_LGKM0; SCHEDB;
    __builtin_amdgcn_s_setprio(1);
#pragma unroll
    for (int mi = 0; mi < 4; ++mi)
#pragma unroll
      for (int ni = 0; ni < 2; ++ni)
#pragma unroll
        for (int ks = 0; ks < 2; ++ks)
          acc[mi + 4][ni + 2] = MFMA(a1[mi][ks], b1[ni][ks], acc[mi + 4][ni + 2]);
    __builtin_amdgcn_s_setprio(0); SCHEDB;

    // all this buffer's LDS reads done (lgkm0 passed) -> free it for kt+2
    BARRIER; SCHEDB;
    if (kt < 6) STAGE(kt + 2, sa, sb);

    // ---- phase 3: pure-register quadrant (M1,N0) covers stage issue ----
    __builtin_amdgcn_s_setprio(1);
#pragma unroll
    for (int mi = 0; mi < 4; ++mi)
#pragma unroll
      for (int ni = 0; ni < 2; ++ni)
#pragma unroll
        for (int ks = 0; ks < 2; ++ks)
          acc[mi + 4][ni] = MFMA(a1[mi][ks], b0[ni][ks], acc[mi + 4][ni]);
    __builtin_amdgcn_s_setprio(0); SCHEDB;

    if (kt < 6) { WAIT_VM8; }       // kt+1 landed; kt+2's 8 may fly
    else if (kt == 6) { WAIT_VM0; } // last tile landed
    SCHEDB;
    if (kt < 7) { BARRIER; SCHEDB; }
  }
#undef STAGE
#undef RDA
#undef RDB

#pragma unroll
  for (int mi = 0; mi < 8; ++mi) {
#pragma unroll
    for (int ni = 0; ni < 4; ++ni) {
      const int col = n0 + wc * 64 + ni * 16 + l15;
      const float bv = bias[col];
      const int rbase = m0 + wr * 128 + mi * 16 + lg * 4;
#pragma unroll
      for (int r = 0; r < 4; ++r) {
        const float v = acc[mi][ni][r] + bv;
        if (MODE == 0) {
          ((u16*)Out)[(size_t)(rbase + r) * ldo + col] = f2bf(v);
        } else {
          ((float*)Out)[(size_t)(rbase + r) * ldo + col] = v;
        }
      }
    }
  }
}

// ---------------- attention: one wave per (window, head), 4 heads/block ----------------
// Swapped QK^T (S^T = K@Q^T) makes softmax j-axis lane-local; V stored pi-permuted in
// LDS so the PV A-fragment is the lane's own packed P values: no barriers, no sP.
// pi(j) = (kt>>1)*32 + lgj*8 + (kt&1)*4 + r  for j = kt*16 + lgj*4 + r.
__global__ __launch_bounds__(256) void attn_kernel(
    const u16* __restrict__ qkv, const float* __restrict__ pbp,
    const float* __restrict__ maskp, u16* __restrict__ attn_out) {
  const int w = threadIdx.x >> 6;
  const int lane = threadIdx.x & 63;
  const int b = blockIdx.x >> 2;
  const int h = ((blockIdx.x & 3) << 2) | w;
  const int l15 = lane & 15, lg = lane >> 4;

  __shared__ u16 sVT[4][32][72];  // per-wave private slab: V^T, pi-permuted columns
  u16 (*vt)[72] = sVT[w];

  // zero own slab (padded columns must be 0; no barrier: wave-private)
  for (int i = lane; i < 1152; i += 64) ((u32*)vt)[i] = 0;

  const size_t rowbase = (size_t)b * (49 * 1536) + h * 32;

  // V scatter: sVT[d][pi(n)] = V[n][d]
  for (int c = lane; c < 196; c += 64) {
    const int n = c >> 2, dg = c & 3;
    u16x8 vv = *reinterpret_cast<const u16x8*>(qkv + rowbase + (size_t)n * 1536 + 1024 + dg * 8);
    const int pin = ((n >> 5) << 5) | ((((n >> 2) & 3)) << 3) | (((n >> 4) & 1) << 2) | (n & 3);
#pragma unroll
    for (int j = 0; j < 8; ++j) vt[dg * 8 + j][pin] = vv[j];
  }

  // Q,K fragments straight from global (rows >=49 clamped; padding handled by maskp)
  bf16x8 aq[4], bk[4];
#pragma unroll
  for (int t = 0; t < 4; ++t) {
    const int i = t * 16 + l15;
    const int r = i < 49 ? i : 48;
    const size_t ro = rowbase + (size_t)r * 1536 + lg * 8;
    aq[t] = *reinterpret_cast<const bf16x8*>(qkv + ro);
    bk[t] = *reinterpret_cast<const bf16x8*>(qkv + ro + 512);
  }

  // V fragments (after scatter; same-wave lgkmcnt ordering)
  bf16x8 bv[2][2];
#pragma unroll
  for (int ni = 0; ni < 2; ++ni)
#pragma unroll
    for (int ks = 0; ks < 2; ++ks)
      bv[ni][ks] = *reinterpret_cast<const bf16x8*>(&vt[ni * 16 + l15][ks * 32 + lg * 8]);

  const float scale = 0.17677669529663687f;
  const float* pbh = pbp + (h << 12);
  const float* mw = maskp + ((size_t)(b & 63) << 12);
  const size_t obase = (size_t)b * 49 * 512 + h * 32;

#pragma unroll
  for (int qt = 0; qt < 4; ++qt) {
    // S^T tile: lane holds S[q=qt*16+l15][j=kt*16+lg*4+r]
    f32x4 sT[4] = {};
#pragma unroll
    for (int kt = 0; kt < 4; ++kt)
      sT[kt] = __builtin_amdgcn_mfma_f32_16x16x32_bf16(bk[kt], aq[qt], sT[kt], 0, 0, 0);

    const int i = qt * 16 + l15;
    const float* pr = pbh + i * 64 + lg * 4;
    const float* mr = mw + i * 64 + lg * 4;
    float v[4][4];
    float mx = -3e38f;
#pragma unroll
    for (int kt = 0; kt < 4; ++kt) {
      f32x4 pv = *reinterpret_cast<const f32x4*>(pr + kt * 16);
      f32x4 mv = *reinterpret_cast<const f32x4*>(mr + kt * 16);
#pragma unroll
      for (int r = 0; r < 4; ++r) {
        const float val = fmaf(sT[kt][r], scale, pv[r] + mv[r]);
        v[kt][r] = val;
        mx = fmaxf(mx, val);
      }
    }
    mx = fmaxf(mx, __shfl_xor(mx, 16));
    mx = fmaxf(mx, __shfl_xor(mx, 32));
    float sum = 0.f;
#pragma unroll
    for (int kt = 0; kt < 4; ++kt)
#pragma unroll
      for (int r = 0; r < 4; ++r) {
        const float e = __expf(v[kt][r] - mx);
        v[kt][r] = e;
        sum += e;
      }
    sum += __shfl_xor(sum, 16);
    sum += __shfl_xor(sum, 32);
    const float rinv = 1.0f / sum;

    // pack normalized P into PV A-fragments (pi-order: lane-local, no shuffles)
    bf16x8 ap[2];
#pragma unroll
    for (int ks = 0; ks < 2; ++ks) {
      u32 w0 = (u32)f2bf(v[2 * ks][0] * rinv) | ((u32)f2bf(v[2 * ks][1] * rinv) << 16);
      u32 w1 = (u32)f2bf(v[2 * ks][2] * rinv) | ((u32)f2bf(v[2 * ks][3] * rinv) << 16);
      u32 w2 = (u32)f2bf(v[2 * ks + 1][0] * rinv) | ((u32)f2bf(v[2 * ks + 1][1] * rinv) << 16);
      u32 w3 = (u32)f2bf(v[2 * ks + 1][2] * rinv) | ((u32)f2bf(v[2 * ks + 1][3] * rinv) << 16);
      union { u32 u[4]; bf16x8 b; } pk;
      pk.u[0] = w0; pk.u[1] = w1; pk.u[2] = w2; pk.u[3] = w3;
      ap[ks] = pk.b;
    }

    // O tile for this q-tile
    f32x4 o[2] = {};
#pragma unroll
    for (int ks = 0; ks < 2; ++ks)
#pragma unroll
      for (int ni = 0; ni < 2; ++ni)
        o[ni] = __builtin_amdgcn_mfma_f32_16x16x32_bf16(ap[ks], bv[ni][ks], o[ni], 0, 0, 0);

#pragma unroll
    for (int r = 0; r < 4; ++r) {
      const int iq = qt * 16 + lg * 4 + r;
      if (iq < 49) {
#pragma unroll
        for (int ni = 0; ni < 2; ++ni)
          attn_out[obase + (size_t)iq * 512 + ni * 16 + l15] = f2bf(o[ni][r]);
      }
    }
  }
}

extern "C" void kernel_launch(void* const* d_in, const int* in_sizes, int n_in,
                              void* d_out, int out_size, void* d_ws, size_t ws_size,
                              hipStream_t stream) {
  (void)in_sizes; (void)n_in; (void)out_size; (void)ws_size;
  const float* x          = (const float*)d_in[0];
  const float* w_qkv      = (const float*)d_in[1];
  const float* b_qkv      = (const float*)d_in[2];
  const float* w_proj     = (const float*)d_in[3];
  const float* b_proj     = (const float*)d_in[4];
  const float* bias_table = (const float*)d_in[5];
  const int*   rel_index  = (const int*)d_in[6];
  const float* mask       = (const float*)d_in[7];

  u16* ws     = (u16*)d_ws;
  u16* xbf    = ws;                    // 51,380,224 elems (reused as attn_out)
  u16* qkv    = ws + 51380224;         // 154,140,672 elems
  u16* wqkvb  = qkv + 154140672;       // 786,432 elems
  u16* wprojb = wqkvb + 786432;        // 262,144 elems
  float* pbp  = (float*)(wprojb + 262144);  // 16*4096 floats
  float* mkp  = pbp + 16 * 4096;            // 64*4096 floats

  // allow 128 KB dynamic LDS (HK-style opt-in; idempotent, host-side)
  (void)hipFuncSetAttribute((const void*)gemm_kernel<0, 6, 49>,
                            hipFuncAttributeMaxDynamicSharedMemorySize, 131072);
  (void)hipFuncSetAttribute((const void*)gemm_kernel<1, 2, 49>,
                            hipFuncAttributeMaxDynamicSharedMemorySize, 131072);

  cvt_kernel<<<2048, 256, 0, stream>>>(x, xbf, 51380224 / 4);
  cvt_kernel<<<192, 256, 0, stream>>>(w_qkv, wqkvb, 786432 / 4);
  cvt_kernel<<<64, 256, 0, stream>>>(w_proj, wprojb, 262144 / 4);
  pbp_kernel<<<16, 256, 0, stream>>>(bias_table, rel_index, pbp);
  maskp_kernel<<<64, 256, 0, stream>>>(mask, mkp);

  // 392 m-tiles = 8 XCDs * 49; GEMM1: 6 n-tiles of 256, GEMM2: 2 n-tiles
  gemm_kernel<0, 6, 49><<<2352, 512, 131072, stream>>>(xbf, wqkvb, b_qkv, qkv, 1536);
  attn_kernel<<<8192, 256, 0, stream>>>(qkv, pbp, mkp, xbf);
  gemm_kernel<1, 2, 49><<<784, 512, 131072, stream>>>(xbf, wprojb, b_proj, d_out, 512);
}

// Round 7
// 514.239 us; speedup vs baseline: 1.3013x; 1.1051x over previous
//
#include <hip/hip_runtime.h>
#include <stdint.h>

typedef unsigned short u16;
typedef unsigned int u32;
typedef unsigned long long u64;
typedef __attribute__((ext_vector_type(4))) u16 u16x4;
typedef __attribute__((ext_vector_type(8))) u16 u16x8;
typedef __attribute__((ext_vector_type(2))) u32 u32x2;
typedef __attribute__((ext_vector_type(8))) short bf16x8;
typedef __attribute__((ext_vector_type(4))) float f32x4;

#define DEVFN __device__ __forceinline__

DEVFN u16 f2bf(float f) {
  union { float f; u32 u; } x; x.f = f;
  u32 u = x.u;
  return (u16)((u + 0x7fffu + ((u >> 16) & 1u)) >> 16);
}
DEVFN float bf2f(u16 v) {
  union { u32 u; float f; } x; x.u = ((u32)v) << 16;
  return x.f;
}

// ---------------- fp32 -> bf16 convert ----------------
__global__ void cvt_kernel(const float* __restrict__ in, u16* __restrict__ out, int n4) {
  const int stride = gridDim.x * blockDim.x;
  for (int i = blockIdx.x * blockDim.x + threadIdx.x; i < n4; i += stride) {
    float4 v = reinterpret_cast<const float4*>(in)[i];
    u16x4 o;
    o.x = f2bf(v.x); o.y = f2bf(v.y); o.z = f2bf(v.z); o.w = f2bf(v.w);
    reinterpret_cast<u16x4*>(out)[i] = o;
  }
}

// ---------------- padded bias table, bf16: pbb[h][i][j64] (pad = 0) ----------------
__global__ void pbb_kernel(const float* __restrict__ bt, const int* __restrict__ ri,
                           u16* __restrict__ pbb) {
  const int h = blockIdx.x;
  for (int t = threadIdx.x; t < 4096; t += 256) {
    const int i = t >> 6, j = t & 63;
    float v = 0.f;
    if (i < 49 && j < 49) v = bt[ri[i * 49 + j] * 16 + h];
    pbb[h * 4096 + t] = f2bf(v);
  }
}

// ---------------- bit-packed mask: mbits[w][i] bit j set == masked (-100) ----------------
__global__ void mbits_kernel(const float* __restrict__ mask, u64* __restrict__ mb) {
  const int w = blockIdx.x;
  const int i = threadIdx.x;  // 0..63
  u64 m = ~0ull << 49;        // padded cols 49..63 flagged (overridden to -1e30 in-kernel)
  if (i < 49) {
    for (int j = 0; j < 49; ++j)
      if (mask[w * 2401 + i * 49 + j] < -1.0f) m |= 1ull << j;
  } else {
    m = ~0ull;
  }
  mb[w * 64 + i] = m;
}

// ---------------- bf16 GEMM: C = A @ Bt^T + bias, K=512 fixed ----------------
// 256x256 tile, 8 waves (2M x 4N), BK=64, double-buffered 128 KB LDS,
// 4-phase quadrant interleave per K-tile, 2-K-tiles-ahead prefetch with
// counted vmcnt(8). XCD-chunked 1-D grid (bid&7 = XCD owns MCHUNK m-tiles).
#define WAIT_LGKM0 asm volatile("s_waitcnt lgkmcnt(0)" ::: "memory")
#define WAIT_VM8   asm volatile("s_waitcnt vmcnt(8)" ::: "memory")
#define WAIT_VM0   asm volatile("s_waitcnt vmcnt(0)" ::: "memory")
#define SCHEDB     __builtin_amdgcn_sched_barrier(0)
#define BARRIER    __builtin_amdgcn_s_barrier()
#define MFMA(a, b, c) __builtin_amdgcn_mfma_f32_16x16x32_bf16(a, b, c, 0, 0, 0)

template <int MODE, int NTILES, int MCHUNK>
__global__ __launch_bounds__(512) void gemm_kernel(
    const u16* __restrict__ A, const u16* __restrict__ Bt,
    const float* __restrict__ bias, void* __restrict__ Out, int ldo) {
  extern __shared__ u16 smem[];  // [buf0 A |buf0 B |buf1 A |buf1 B] x 16384 u16
  const int tid = threadIdx.x;
  const int lane = tid & 63;
  const int wid = tid >> 6;
  const int bid = blockIdx.x;
  const int xcd = bid & 7;
  const int slot = bid >> 3;
  const int m0 = (xcd * MCHUNK + slot / NTILES) * 256;
  const int n0 = (slot % NTILES) * 256;
  const int wr = wid >> 2, wc = wid & 3;  // wave -> (2M x 4N) sub-grid
  const int l15 = lane & 15, lg = lane >> 4;
  const int rg0 = tid >> 3;  // staging row within 64-row round
  const int sl0 = tid & 7;   // staging 16B slot within 128B row

  f32x4 acc[8][4] = {};

  u16* const sA0 = smem;
  u16* const sB0 = smem + 16384;
  u16* const sA1 = smem + 32768;
  u16* const sB1 = smem + 49152;

#define STAGE(kt_, sa_, sb_)                                                   \
  {                                                                            \
    _Pragma("unroll") for (int i = 0; i < 4; ++i) {                            \
      const int rg = i * 64 + rg0;                                             \
      const int kc = sl0 ^ (rg & 7);                                           \
      const u16* ga = A + (size_t)(m0 + rg) * 512 + (kt_) * 64 + kc * 8;       \
      __builtin_amdgcn_global_load_lds(                                        \
          (const __attribute__((address_space(1))) void*)ga,                   \
          (__attribute__((address_space(3))) void*)((sa_) + i * 4096 + wid * 512), \
          16, 0, 0);                                                           \
    }                                                                          \
    _Pragma("unroll") for (int i = 0; i < 4; ++i) {                            \
      const int rg = i * 64 + rg0;                                             \
      const int kc = sl0 ^ (rg & 7);                                           \
      const u16* gb = Bt + (size_t)(n0 + rg) * 512 + (kt_) * 64 + kc * 8;      \
      __builtin_amdgcn_global_load_lds(                                        \
          (const __attribute__((address_space(1))) void*)gb,                   \
          (__attribute__((address_space(3))) void*)((sb_) + i * 4096 + wid * 512), \
          16, 0, 0);                                                           \
    }                                                                          \
  }

#define RDA(dst, sa_, mi, ks)                                                  \
  {                                                                            \
    const int row_ = wr * 128 + (mi) * 16 + l15;                               \
    dst = *reinterpret_cast<const bf16x8*>(                                    \
        (sa_) + row_ * 64 + ((((ks) * 4 + lg) ^ (row_ & 7)) << 3));            \
  }
#define RDB(dst, sb_, ni, ks)                                                  \
  {                                                                            \
    const int row_ = wc * 64 + (ni) * 16 + l15;                                \
    dst = *reinterpret_cast<const bf16x8*>(                                    \
        (sb_) + row_ * 64 + ((((ks) * 4 + lg) ^ (row_ & 7)) << 3));            \
  }

  STAGE(0, sA0, sB0);
  STAGE(1, sA1, sB1);
  WAIT_VM8; SCHEDB;  // K-tile 0 landed (own 8 of tile 1 may still fly)
  BARRIER; SCHEDB;   // all waves' tile 0 landed

#pragma unroll
  for (int kt = 0; kt < 8; ++kt) {
    u16* const sa = (kt & 1) ? sA1 : sA0;
    u16* const sb = (kt & 1) ? sB1 : sB0;
    bf16x8 a0[4][2], a1[4][2], b0[2][2], b1[2][2];

    // ---- phase 0: A-half0 + B-half0 -> quadrant (M0,N0) ----
#pragma unroll
    for (int mi = 0; mi < 4; ++mi) { RDA(a0[mi][0], sa, mi, 0); RDA(a0[mi][1], sa, mi, 1); }
#pragma unroll
    for (int ni = 0; ni < 2; ++ni) { RDB(b0[ni][0], sb, ni, 0); RDB(b0[ni][1], sb, ni, 1); }
    WAIT_LGKM0; SCHEDB;
    __builtin_amdgcn_s_setprio(1);
#pragma unroll
    for (int mi = 0; mi < 4; ++mi)
#pragma unroll
      for (int ni = 0; ni < 2; ++ni)
#pragma unroll
        for (int ks = 0; ks < 2; ++ks)
          acc[mi][ni] = MFMA(a0[mi][ks], b0[ni][ks], acc[mi][ni]);
    __builtin_amdgcn_s_setprio(0); SCHEDB;

    // ---- phase 1: B-half1 -> quadrant (M0,N1) ----
#pragma unroll
    for (int ni = 0; ni < 2; ++ni) { RDB(b1[ni][0], sb, ni + 2, 0); RDB(b1[ni][1], sb, ni + 2, 1); }
    WAIT_LGKM0; SCHEDB;
    __builtin_amdgcn_s_setprio(1);
#pragma unroll
    for (int mi = 0; mi < 4; ++mi)
#pragma unroll
      for (int ni = 0; ni < 2; ++ni)
#pragma unroll
        for (int ks = 0; ks < 2; ++ks)
          acc[mi][ni + 2] = MFMA(a0[mi][ks], b1[ni][ks], acc[mi][ni + 2]);
    __builtin_amdgcn_s_setprio(0); SCHEDB;

    // ---- phase 2: A-half1 -> quadrant (M1,N1) ----
#pragma unroll
    for (int mi = 0; mi < 4; ++mi) { RDA(a1[mi][0], sa, mi + 4, 0); RDA(a1[mi][1], sa, mi + 4, 1); }
    WAIT_LGKM0; SCHEDB;
    __builtin_amdgcn_s_setprio(1);
#pragma unroll
    for (int mi = 0; mi < 4; ++mi)
#pragma unroll
      for (int ni = 0; ni < 2; ++ni)
#pragma unroll
        for (int ks = 0; ks < 2; ++ks)
          acc[mi + 4][ni + 2] = MFMA(a1[mi][ks], b1[ni][ks], acc[mi + 4][ni + 2]);
    __builtin_amdgcn_s_setprio(0); SCHEDB;

    // all this buffer's LDS reads done (lgkm0 passed) -> free it for kt+2
    BARRIER; SCHEDB;
    if (kt < 6) STAGE(kt + 2, sa, sb);

    // ---- phase 3: pure-register quadrant (M1,N0) covers stage issue ----
    __builtin_amdgcn_s_setprio(1);
#pragma unroll
    for (int mi = 0; mi < 4; ++mi)
#pragma unroll
      for (int ni = 0; ni < 2; ++ni)
#pragma unroll
        for (int ks = 0; ks < 2; ++ks)
          acc[mi + 4][ni] = MFMA(a1[mi][ks], b0[ni][ks], acc[mi + 4][ni]);
    __builtin_amdgcn_s_setprio(0); SCHEDB;

    if (kt < 6) { WAIT_VM8; }       // kt+1 landed; kt+2's 8 may fly
    else if (kt == 6) { WAIT_VM0; } // last tile landed
    SCHEDB;
    if (kt < 7) { BARRIER; SCHEDB; }
  }
#undef STAGE
#undef RDA
#undef RDB

#pragma unroll
  for (int mi = 0; mi < 8; ++mi) {
#pragma unroll
    for (int ni = 0; ni < 4; ++ni) {
      const int col = n0 + wc * 64 + ni * 16 + l15;
      const float bv = bias[col];
      const int rbase = m0 + wr * 128 + mi * 16 + lg * 4;
#pragma unroll
      for (int r = 0; r < 4; ++r) {
        const float v = acc[mi][ni][r] + bv;
        if (MODE == 0) {
          ((u16*)Out)[(size_t)(rbase + r) * ldo + col] = f2bf(v);
        } else {
          ((float*)Out)[(size_t)(rbase + r) * ldo + col] = v;
        }
      }
    }
  }
}

// ---------------- attention: one wave per (window, head), 4 heads/block ----------------
// Swapped QK^T (S^T = K@Q^T) makes softmax j-axis lane-local; V stored pi-permuted in
// LDS so the PV A-fragment is the lane's own packed P values: no barriers, no sP.
// Score tables: bf16 bias (pbb) + bit-packed mask (mbits) -> ~2.6 KB/wave of L2
// table reads instead of 32 KB (the round-6 L2-BW bottleneck).
__global__ __launch_bounds__(256) void attn_kernel(
    const u16* __restrict__ qkv, const u16* __restrict__ pbb,
    const u64* __restrict__ mbits, u16* __restrict__ attn_out) {
  const int w = threadIdx.x >> 6;
  const int lane = threadIdx.x & 63;
  const int b = blockIdx.x >> 2;
  const int h = ((blockIdx.x & 3) << 2) | w;
  const int l15 = lane & 15, lg = lane >> 4;
  const int lg4 = lg * 4;

  __shared__ u16 sVT[4][32][72];  // per-wave private slab: V^T, pi-permuted columns
  u16 (*vt)[72] = sVT[w];

  // zero own slab (padded columns must be 0; no barrier: wave-private)
  for (int i = lane; i < 1152; i += 64) ((u32*)vt)[i] = 0;

  const size_t rowbase = (size_t)b * (49 * 1536) + h * 32;

  // V scatter: sVT[d][pi(n)] = V[n][d]
  for (int c = lane; c < 196; c += 64) {
    const int n = c >> 2, dg = c & 3;
    u16x8 vv = *reinterpret_cast<const u16x8*>(qkv + rowbase + (size_t)n * 1536 + 1024 + dg * 8);
    const int pin = ((n >> 5) << 5) | ((((n >> 2) & 3)) << 3) | (((n >> 4) & 1) << 2) | (n & 3);
#pragma unroll
    for (int j = 0; j < 8; ++j) vt[dg * 8 + j][pin] = vv[j];
  }

  // Q,K fragments straight from global (rows >=49 clamped; padding handled below)
  bf16x8 aq[4], bk[4];
#pragma unroll
  for (int t = 0; t < 4; ++t) {
    const int i = t * 16 + l15;
    const int r = i < 49 ? i : 48;
    const size_t ro = rowbase + (size_t)r * 1536 + lg * 8;
    aq[t] = *reinterpret_cast<const bf16x8*>(qkv + ro);
    bk[t] = *reinterpret_cast<const bf16x8*>(qkv + ro + 512);
  }

  // mask bit-rows for all 4 q-tiles (hoisted: 4 x 8B, independent of MFMA)
  const u64* mwb = mbits + ((b & 63) << 6);
  u64 mb[4];
#pragma unroll
  for (int qt = 0; qt < 4; ++qt) mb[qt] = mwb[qt * 16 + l15];

  // V fragments (after scatter; same-wave lgkmcnt ordering)
  bf16x8 bv[2][2];
#pragma unroll
  for (int ni = 0; ni < 2; ++ni)
#pragma unroll
    for (int ks = 0; ks < 2; ++ks)
      bv[ni][ks] = *reinterpret_cast<const bf16x8*>(&vt[ni * 16 + l15][ks * 32 + lg * 8]);

  const float scale = 0.17677669529663687f;
  const u16* pbh = pbb + (h << 12);
  const size_t obase = (size_t)b * 49 * 512 + h * 32;

#pragma unroll
  for (int qt = 0; qt < 4; ++qt) {
    // S^T tile: lane holds S[q=qt*16+l15][j=kt*16+lg4+r]
    f32x4 sT[4] = {};
#pragma unroll
    for (int kt = 0; kt < 4; ++kt)
      sT[kt] = __builtin_amdgcn_mfma_f32_16x16x32_bf16(bk[kt], aq[qt], sT[kt], 0, 0, 0);

    const int i = qt * 16 + l15;
    const u16* pr = pbh + i * 64 + lg4;
    float v[4][4];
    float mx = -3e38f;
#pragma unroll
    for (int kt = 0; kt < 4; ++kt) {
      u16x4 pv = *reinterpret_cast<const u16x4*>(pr + kt * 16);
      const u32 nib = (u32)(mb[qt] >> (kt * 16 + lg4)) & 0xFu;
#pragma unroll
      for (int r = 0; r < 4; ++r) {
        float val = fmaf(sT[kt][r], scale, bf2f(pv[r]));
        if (nib & (1u << r)) val -= 100.f;          // shift-window mask, exact
        if (kt == 3 && (lg4 + r) >= 1) val = -1e30f; // j>=49 padding -> zero weight
        v[kt][r] = val;
        mx = fmaxf(mx, val);
      }
    }
    mx = fmaxf(mx, __shfl_xor(mx, 16));
    mx = fmaxf(mx, __shfl_xor(mx, 32));
    float sum = 0.f;
#pragma unroll
    for (int kt = 0; kt < 4; ++kt)
#pragma unroll
      for (int r = 0; r < 4; ++r) {
        const float e = __expf(v[kt][r] - mx);
        v[kt][r] = e;
        sum += e;
      }
    sum += __shfl_xor(sum, 16);
    sum += __shfl_xor(sum, 32);
    const float rinv = 1.0f / sum;

    // pack normalized P into PV A-fragments (pi-order: lane-local, no shuffles)
    bf16x8 ap[2];
#pragma unroll
    for (int ks = 0; ks < 2; ++ks) {
      u32 w0 = (u32)f2bf(v[2 * ks][0] * rinv) | ((u32)f2bf(v[2 * ks][1] * rinv) << 16);
      u32 w1 = (u32)f2bf(v[2 * ks][2] * rinv) | ((u32)f2bf(v[2 * ks][3] * rinv) << 16);
      u32 w2 = (u32)f2bf(v[2 * ks + 1][0] * rinv) | ((u32)f2bf(v[2 * ks + 1][1] * rinv) << 16);
      u32 w3 = (u32)f2bf(v[2 * ks + 1][2] * rinv) | ((u32)f2bf(v[2 * ks + 1][3] * rinv) << 16);
      union { u32 u[4]; bf16x8 b; } pk;
      pk.u[0] = w0; pk.u[1] = w1; pk.u[2] = w2; pk.u[3] = w3;
      ap[ks] = pk.b;
    }

    // O tile for this q-tile
    f32x4 o[2] = {};
#pragma unroll
    for (int ks = 0; ks < 2; ++ks)
#pragma unroll
      for (int ni = 0; ni < 2; ++ni)
        o[ni] = __builtin_amdgcn_mfma_f32_16x16x32_bf16(ap[ks], bv[ni][ks], o[ni], 0, 0, 0);

#pragma unroll
    for (int r = 0; r < 4; ++r) {
      const int iq = qt * 16 + lg4 + r;
      if (iq < 49) {
#pragma unroll
        for (int ni = 0; ni < 2; ++ni)
          attn_out[obase + (size_t)iq * 512 + ni * 16 + l15] = f2bf(o[ni][r]);
      }
    }
  }
}

extern "C" void kernel_launch(void* const* d_in, const int* in_sizes, int n_in,
                              void* d_out, int out_size, void* d_ws, size_t ws_size,
                              hipStream_t stream) {
  (void)in_sizes; (void)n_in; (void)out_size; (void)ws_size;
  const float* x          = (const float*)d_in[0];
  const float* w_qkv      = (const float*)d_in[1];
  const float* b_qkv      = (const float*)d_in[2];
  const float* w_proj     = (const float*)d_in[3];
  const float* b_proj     = (const float*)d_in[4];
  const float* bias_table = (const float*)d_in[5];
  const int*   rel_index  = (const int*)d_in[6];
  const float* mask       = (const float*)d_in[7];

  u16* ws     = (u16*)d_ws;
  u16* xbf    = ws;                    // 51,380,224 elems (reused as attn_out)
  u16* qkv    = ws + 51380224;         // 154,140,672 elems
  u16* wqkvb  = qkv + 154140672;       // 786,432 elems
  u16* wprojb = wqkvb + 786432;        // 262,144 elems
  u16* pbb    = wprojb + 262144;       // 16*4096 bf16 (128 KB)
  u64* mbits  = (u64*)(pbb + 65536);   // 64*64 u64 (32 KB), 8B-aligned

  // allow 128 KB dynamic LDS (HK-style opt-in; idempotent, host-side)
  (void)hipFuncSetAttribute((const void*)gemm_kernel<0, 6, 49>,
                            hipFuncAttributeMaxDynamicSharedMemorySize, 131072);
  (void)hipFuncSetAttribute((const void*)gemm_kernel<1, 2, 49>,
                            hipFuncAttributeMaxDynamicSharedMemorySize, 131072);

  cvt_kernel<<<2048, 256, 0, stream>>>(x, xbf, 51380224 / 4);
  cvt_kernel<<<192, 256, 0, stream>>>(w_qkv, wqkvb, 786432 / 4);
  cvt_kernel<<<64, 256, 0, stream>>>(w_proj, wprojb, 262144 / 4);
  pbb_kernel<<<16, 256, 0, stream>>>(bias_table, rel_index, pbb);
  mbits_kernel<<<64, 64, 0, stream>>>(mask, mbits);

  // 392 m-tiles = 8 XCDs * 49; GEMM1: 6 n-tiles of 256, GEMM2: 2 n-tiles
  gemm_kernel<0, 6, 49><<<2352, 512, 131072, stream>>>(xbf, wqkvb, b_qkv, qkv, 1536);
  attn_kernel<<<8192, 256, 0, stream>>>(qkv, pbb, mbits, xbf);
  gemm_kernel<1, 2, 49><<<784, 512, 131072, stream>>>(xbf, wprojb, b_proj, d_out, 512);
}

// Round 8
// 505.427 us; speedup vs baseline: 1.3239x; 1.0174x over previous
//
#include <hip/hip_runtime.h>
#include <stdint.h>

typedef unsigned short u16;
typedef unsigned int u32;
typedef unsigned long long u64;
typedef __attribute__((ext_vector_type(4))) u16 u16x4;
typedef __attribute__((ext_vector_type(8))) u16 u16x8;
typedef __attribute__((ext_vector_type(2))) u32 u32x2;
typedef __attribute__((ext_vector_type(8))) short bf16x8;
typedef __attribute__((ext_vector_type(4))) float f32x4;

#define DEVFN __device__ __forceinline__

DEVFN u16 f2bf(float f) {
  union { float f; u32 u; } x; x.f = f;
  u32 u = x.u;
  return (u16)((u + 0x7fffu + ((u >> 16) & 1u)) >> 16);
}
DEVFN float bf2f(u16 v) {
  union { u32 u; float f; } x; x.u = ((u32)v) << 16;
  return x.f;
}

// ---------------- fp32 -> bf16 convert ----------------
__global__ void cvt_kernel(const float* __restrict__ in, u16* __restrict__ out, int n4) {
  const int stride = gridDim.x * blockDim.x;
  for (int i = blockIdx.x * blockDim.x + threadIdx.x; i < n4; i += stride) {
    float4 v = reinterpret_cast<const float4*>(in)[i];
    u16x4 o;
    o.x = f2bf(v.x); o.y = f2bf(v.y); o.z = f2bf(v.z); o.w = f2bf(v.w);
    reinterpret_cast<u16x4*>(out)[i] = o;
  }
}

// ---------------- padded bias table, bf16: pbb[h][i][j64] (pad = 0) ----------------
__global__ void pbb_kernel(const float* __restrict__ bt, const int* __restrict__ ri,
                           u16* __restrict__ pbb) {
  const int h = blockIdx.x;
  for (int t = threadIdx.x; t < 4096; t += 256) {
    const int i = t >> 6, j = t & 63;
    float v = 0.f;
    if (i < 49 && j < 49) v = bt[ri[i * 49 + j] * 16 + h];
    pbb[h * 4096 + t] = f2bf(v);
  }
}

// ---------------- bit-packed mask: mbits[w][i] bit j set == masked (-100) ----------------
__global__ void mbits_kernel(const float* __restrict__ mask, u64* __restrict__ mb) {
  const int w = blockIdx.x;
  const int i = threadIdx.x;  // 0..63
  u64 m = ~0ull << 49;
  if (i < 49) {
    for (int j = 0; j < 49; ++j)
      if (mask[w * 2401 + i * 49 + j] < -1.0f) m |= 1ull << j;
  } else {
    m = ~0ull;
  }
  mb[w * 64 + i] = m;
}

// ---------------- bf16 GEMM: C = A @ Bt^T + bias, K=512 fixed ----------------
// 256x256 tile, 8 waves (2M x 4N), BK=64, dbuf 128 KB LDS, m201-style 8-phase
// schedule: per K-tile 4 phases {reads; stage 1 half-tile; bar; lgkm0; 16 MFMA;
// bar}, vmcnt(2) at each K-tile's last phase. Stage stream offset by 3 phases
// (into buf[t&1] only after all reads of K-tile t done at P3's end-barrier).
// XCD-chunked 1-D grid.
#define WAIT_LGKM0 asm volatile("s_waitcnt lgkmcnt(0)" ::: "memory")
#define WAIT_LGKM8 asm volatile("s_waitcnt lgkmcnt(8)" ::: "memory")
#define WAIT_VM2   asm volatile("s_waitcnt vmcnt(2)" ::: "memory")
#define WAIT_VM0   asm volatile("s_waitcnt vmcnt(0)" ::: "memory")
#define SCHEDB     __builtin_amdgcn_sched_barrier(0)
#define BARRIER    __builtin_amdgcn_s_barrier()
#define MFMA(a, b, c) __builtin_amdgcn_mfma_f32_16x16x32_bf16(a, b, c, 0, 0, 0)

template <int MODE, int NTILES, int MCHUNK>
__global__ __launch_bounds__(512) void gemm_kernel(
    const u16* __restrict__ A, const u16* __restrict__ Bt,
    const float* __restrict__ bias, void* __restrict__ Out, int ldo) {
  extern __shared__ u16 smem[];  // per buffer: A 256x64 | B 256x64 (32768 u16); 2 buffers
  const int tid = threadIdx.x;
  const int lane = tid & 63;
  const int wid = tid >> 6;
  const int bid = blockIdx.x;
  const int xcd = bid & 7;
  const int slot = bid >> 3;
  const int m0 = (xcd * MCHUNK + slot / NTILES) * 256;
  const int n0 = (slot % NTILES) * 256;
  const int wr = wid >> 2, wc = wid & 3;  // wave -> (2M x 4N)
  const int l15 = lane & 15, lg = lane >> 4;
  const int rg0 = tid >> 3;  // staging row within 64-row round
  const int sl0 = tid & 7;   // staging 16B slot within 128B row

  f32x4 acc[8][4] = {};

  // half parts: 0=A rows 0-127, 1=A rows 128-255, 2=B rows 0-127, 3=B rows 128-255
#define STAGE_RAW(kt_, hp_)                                                    \
  {                                                                            \
    const u16* srcp_ = ((hp_) < 2)                                             \
        ? (A + (size_t)(m0 + ((hp_) & 1) * 128) * 512)                         \
        : (Bt + (size_t)(n0 + ((hp_) & 1) * 128) * 512);                       \
    u16* dst_ = smem + ((kt_) & 1) * 32768 + (hp_) * 8192;                     \
    _Pragma("unroll") for (int i_ = 0; i_ < 2; ++i_) {                         \
      const int rg_ = i_ * 64 + rg0;                                           \
      const int kc_ = sl0 ^ (rg_ & 7);                                         \
      const u16* g_ = srcp_ + (size_t)rg_ * 512 + (kt_) * 64 + kc_ * 8;        \
      __builtin_amdgcn_global_load_lds(                                        \
          (const __attribute__((address_space(1))) void*)g_,                   \
          (__attribute__((address_space(3))) void*)(dst_ + i_ * 4096 + wid * 512), \
          16, 0, 0);                                                           \
    }                                                                          \
  }

  // stage stream: s-th half-tile (s = g-3, g = global phase) = K-tile 2+s/4, part s&3
#define STG(g_)                                                                \
  if ((g_) >= 3 && (g_) < 27) {                                                \
    const int s_ = (g_) - 3;                                                   \
    STAGE_RAW(2 + s_ / 4, s_ & 3);                                             \
  }

#define RDA(dst, mi_, ks_)                                                     \
  {                                                                            \
    const int row_ = wr * 128 + (mi_) * 16 + l15;                              \
    dst = *reinterpret_cast<const bf16x8*>(                                    \
        smem + cb + row_ * 64 + ((((ks_) * 4 + lg) ^ (row_ & 7)) << 3));       \
  }
#define RDB(dst, ni_, ks_)                                                     \
  {                                                                            \
    const int row_ = wc * 64 + (ni_) * 16 + l15;                               \
    dst = *reinterpret_cast<const bf16x8*>(                                    \
        smem + cb + 16384 + row_ * 64 + ((((ks_) * 4 + lg) ^ (row_ & 7)) << 3)); \
  }

  // prologue: K-tiles 0,1 fully staged, drained
#pragma unroll
  for (int hp = 0; hp < 4; ++hp) STAGE_RAW(0, hp);
#pragma unroll
  for (int hp = 0; hp < 4; ++hp) STAGE_RAW(1, hp);
  WAIT_VM0; SCHEDB;
  BARRIER; SCHEDB;

#pragma unroll
  for (int kt = 0; kt < 8; ++kt) {
    const int cb = (kt & 1) * 32768;
    const int g0 = kt * 4;
    bf16x8 a0[4][2], a1[4][2], b0[2][2], b1[2][2];

    // ---- P1: reads A-low(8) + B-low(4); quad (M0,N0) ----
#pragma unroll
    for (int mi = 0; mi < 4; ++mi) { RDA(a0[mi][0], mi, 0); RDA(a0[mi][1], mi, 1); }
#pragma unroll
    for (int ni = 0; ni < 2; ++ni) { RDB(b0[ni][0], ni, 0); RDB(b0[ni][1], ni, 1); }
    STG(g0 + 0);
    WAIT_LGKM8; SCHEDB;
    BARRIER;
    WAIT_LGKM0; SCHEDB;
    __builtin_amdgcn_s_setprio(1);
#pragma unroll
    for (int mi = 0; mi < 4; ++mi)
#pragma unroll
      for (int ni = 0; ni < 2; ++ni)
#pragma unroll
        for (int ks = 0; ks < 2; ++ks)
          acc[mi][ni] = MFMA(a0[mi][ks], b0[ni][ks], acc[mi][ni]);
    __builtin_amdgcn_s_setprio(0); SCHEDB;
    BARRIER; SCHEDB;

    // ---- P2: reads B-high(4); quad (M0,N1) ----
#pragma unroll
    for (int ni = 0; ni < 2; ++ni) { RDB(b1[ni][0], ni + 2, 0); RDB(b1[ni][1], ni + 2, 1); }
    STG(g0 + 1);
    BARRIER;
    WAIT_LGKM0; SCHEDB;
    __builtin_amdgcn_s_setprio(1);
#pragma unroll
    for (int mi = 0; mi < 4; ++mi)
#pragma unroll
      for (int ni = 0; ni < 2; ++ni)
#pragma unroll
        for (int ks = 0; ks < 2; ++ks)
          acc[mi][ni + 2] = MFMA(a0[mi][ks], b1[ni][ks], acc[mi][ni + 2]);
    __builtin_amdgcn_s_setprio(0); SCHEDB;
    BARRIER; SCHEDB;

    // ---- P3: reads A-high(8); quad (M1,N1) ----
#pragma unroll
    for (int mi = 0; mi < 4; ++mi) { RDA(a1[mi][0], mi + 4, 0); RDA(a1[mi][1], mi + 4, 1); }
    STG(g0 + 2);
    BARRIER;
    WAIT_LGKM0; SCHEDB;
    __builtin_amdgcn_s_setprio(1);
#pragma unroll
    for (int mi = 0; mi < 4; ++mi)
#pragma unroll
      for (int ni = 0; ni < 2; ++ni)
#pragma unroll
        for (int ks = 0; ks < 2; ++ks)
          acc[mi + 4][ni + 2] = MFMA(a1[mi][ks], b1[ni][ks], acc[mi + 4][ni + 2]);
    __builtin_amdgcn_s_setprio(0); SCHEDB;
    BARRIER; SCHEDB;

    // ---- P4: no reads; quad (M1,N0) from live regs; vmcnt once per K-tile ----
    STG(g0 + 3);
    BARRIER; SCHEDB;
    __builtin_amdgcn_s_setprio(1);
#pragma unroll
    for (int mi = 0; mi < 4; ++mi)
#pragma unroll
      for (int ni = 0; ni < 2; ++ni)
#pragma unroll
        for (int ks = 0; ks < 2; ++ks)
          acc[mi + 4][ni] = MFMA(a1[mi][ks], b0[ni][ks], acc[mi + 4][ni]);
    __builtin_amdgcn_s_setprio(0); SCHEDB;
    if (g0 + 3 == 27) { WAIT_VM0; }            // drain last prefetch (K7)
    else if (g0 + 3 < 27) { WAIT_VM2; }        // confirm next K-tile's 4 halves
    SCHEDB;
    BARRIER; SCHEDB;
  }
#undef STAGE_RAW
#undef STG
#undef RDA
#undef RDB

#pragma unroll
  for (int mi = 0; mi < 8; ++mi) {
#pragma unroll
    for (int ni = 0; ni < 4; ++ni) {
      const int col = n0 + wc * 64 + ni * 16 + l15;
      const float bv = bias[col];
      const int rbase = m0 + wr * 128 + mi * 16 + lg * 4;
#pragma unroll
      for (int r = 0; r < 4; ++r) {
        const float v = acc[mi][ni][r] + bv;
        if (MODE == 0) {
          ((u16*)Out)[(size_t)(rbase + r) * ldo + col] = f2bf(v);
        } else {
          ((float*)Out)[(size_t)(rbase + r) * ldo + col] = v;
        }
      }
    }
  }
}

// ---------------- attention: one wave per (window, head), 4 heads/block ----------------
// Swapped QK^T (S^T = K@Q^T) makes softmax j-axis lane-local; V stored pi-permuted in
// LDS so the PV A-fragment is the lane's own packed P values: no barriers, no sP.
// Score tables: bf16 bias (pbb) + bit-packed mask (mbits).
__global__ __launch_bounds__(256) void attn_kernel(
    const u16* __restrict__ qkv, const u16* __restrict__ pbb,
    const u64* __restrict__ mbits, u16* __restrict__ attn_out) {
  const int w = threadIdx.x >> 6;
  const int lane = threadIdx.x & 63;
  const int b = blockIdx.x >> 2;
  const int h = ((blockIdx.x & 3) << 2) | w;
  const int l15 = lane & 15, lg = lane >> 4;
  const int lg4 = lg * 4;

  __shared__ u16 sVT[4][32][72];
  u16 (*vt)[72] = sVT[w];

  for (int i = lane; i < 1152; i += 64) ((u32*)vt)[i] = 0;

  const size_t rowbase = (size_t)b * (49 * 1536) + h * 32;

  for (int c = lane; c < 196; c += 64) {
    const int n = c >> 2, dg = c & 3;
    u16x8 vv = *reinterpret_cast<const u16x8*>(qkv + rowbase + (size_t)n * 1536 + 1024 + dg * 8);
    const int pin = ((n >> 5) << 5) | ((((n >> 2) & 3)) << 3) | (((n >> 4) & 1) << 2) | (n & 3);
#pragma unroll
    for (int j = 0; j < 8; ++j) vt[dg * 8 + j][pin] = vv[j];
  }

  bf16x8 aq[4], bk[4];
#pragma unroll
  for (int t = 0; t < 4; ++t) {
    const int i = t * 16 + l15;
    const int r = i < 49 ? i : 48;
    const size_t ro = rowbase + (size_t)r * 1536 + lg * 8;
    aq[t] = *reinterpret_cast<const bf16x8*>(qkv + ro);
    bk[t] = *reinterpret_cast<const bf16x8*>(qkv + ro + 512);
  }

  const u64* mwb = mbits + ((b & 63) << 6);
  u64 mb[4];
#pragma unroll
  for (int qt = 0; qt < 4; ++qt) mb[qt] = mwb[qt * 16 + l15];

  bf16x8 bv[2][2];
#pragma unroll
  for (int ni = 0; ni < 2; ++ni)
#pragma unroll
    for (int ks = 0; ks < 2; ++ks)
      bv[ni][ks] = *reinterpret_cast<const bf16x8*>(&vt[ni * 16 + l15][ks * 32 + lg * 8]);

  const float scale = 0.17677669529663687f;
  const u16* pbh = pbb + (h << 12);
  const size_t obase = (size_t)b * 49 * 512 + h * 32;

#pragma unroll
  for (int qt = 0; qt < 4; ++qt) {
    f32x4 sT[4] = {};
#pragma unroll
    for (int kt = 0; kt < 4; ++kt)
      sT[kt] = __builtin_amdgcn_mfma_f32_16x16x32_bf16(bk[kt], aq[qt], sT[kt], 0, 0, 0);

    const int i = qt * 16 + l15;
    const u16* pr = pbh + i * 64 + lg4;
    float v[4][4];
    float mx = -3e38f;
#pragma unroll
    for (int kt = 0; kt < 4; ++kt) {
      u16x4 pv = *reinterpret_cast<const u16x4*>(pr + kt * 16);
      const u32 nib = (u32)(mb[qt] >> (kt * 16 + lg4)) & 0xFu;
#pragma unroll
      for (int r = 0; r < 4; ++r) {
        float val = fmaf(sT[kt][r], scale, bf2f(pv[r]));
        if (nib & (1u << r)) val -= 100.f;
        if (kt == 3 && (lg4 + r) >= 1) val = -1e30f;
        v[kt][r] = val;
        mx = fmaxf(mx, val);
      }
    }
    mx = fmaxf(mx, __shfl_xor(mx, 16));
    mx = fmaxf(mx, __shfl_xor(mx, 32));
    float sum = 0.f;
#pragma unroll
    for (int kt = 0; kt < 4; ++kt)
#pragma unroll
      for (int r = 0; r < 4; ++r) {
        const float e = __expf(v[kt][r] - mx);
        v[kt][r] = e;
        sum += e;
      }
    sum += __shfl_xor(sum, 16);
    sum += __shfl_xor(sum, 32);
    const float rinv = 1.0f / sum;

    bf16x8 ap[2];
#pragma unroll
    for (int ks = 0; ks < 2; ++ks) {
      u32 w0 = (u32)f2bf(v[2 * ks][0] * rinv) | ((u32)f2bf(v[2 * ks][1] * rinv) << 16);
      u32 w1 = (u32)f2bf(v[2 * ks][2] * rinv) | ((u32)f2bf(v[2 * ks][3] * rinv) << 16);
      u32 w2 = (u32)f2bf(v[2 * ks + 1][0] * rinv) | ((u32)f2bf(v[2 * ks + 1][1] * rinv) << 16);
      u32 w3 = (u32)f2bf(v[2 * ks + 1][2] * rinv) | ((u32)f2bf(v[2 * ks + 1][3] * rinv) << 16);
      union { u32 u[4]; bf16x8 b; } pk;
      pk.u[0] = w0; pk.u[1] = w1; pk.u[2] = w2; pk.u[3] = w3;
      ap[ks] = pk.b;
    }

    f32x4 o[2] = {};
#pragma unroll
    for (int ks = 0; ks < 2; ++ks)
#pragma unroll
      for (int ni = 0; ni < 2; ++ni)
        o[ni] = __builtin_amdgcn_mfma_f32_16x16x32_bf16(ap[ks], bv[ni][ks], o[ni], 0, 0, 0);

#pragma unroll
    for (int r = 0; r < 4; ++r) {
      const int iq = qt * 16 + lg4 + r;
      if (iq < 49) {
#pragma unroll
        for (int ni = 0; ni < 2; ++ni)
          attn_out[obase + (size_t)iq * 512 + ni * 16 + l15] = f2bf(o[ni][r]);
      }
    }
  }
}

extern "C" void kernel_launch(void* const* d_in, const int* in_sizes, int n_in,
                              void* d_out, int out_size, void* d_ws, size_t ws_size,
                              hipStream_t stream) {
  (void)in_sizes; (void)n_in; (void)out_size; (void)ws_size;
  const float* x          = (const float*)d_in[0];
  const float* w_qkv      = (const float*)d_in[1];
  const float* b_qkv      = (const float*)d_in[2];
  const float* w_proj     = (const float*)d_in[3];
  const float* b_proj     = (const float*)d_in[4];
  const float* bias_table = (const float*)d_in[5];
  const int*   rel_index  = (const int*)d_in[6];
  const float* mask       = (const float*)d_in[7];

  u16* ws     = (u16*)d_ws;
  u16* xbf    = ws;                    // 51,380,224 elems (reused as attn_out)
  u16* qkv    = ws + 51380224;         // 154,140,672 elems
  u16* wqkvb  = qkv + 154140672;       // 786,432 elems
  u16* wprojb = wqkvb + 786432;        // 262,144 elems
  u16* pbb    = wprojb + 262144;       // 16*4096 bf16 (128 KB)
  u64* mbits  = (u64*)(pbb + 65536);   // 64*64 u64 (32 KB), 8B-aligned

  (void)hipFuncSetAttribute((const void*)gemm_kernel<0, 6, 49>,
                            hipFuncAttributeMaxDynamicSharedMemorySize, 131072);
  (void)hipFuncSetAttribute((const void*)gemm_kernel<1, 2, 49>,
                            hipFuncAttributeMaxDynamicSharedMemorySize, 131072);

  cvt_kernel<<<2048, 256, 0, stream>>>(x, xbf, 51380224 / 4);
  cvt_kernel<<<192, 256, 0, stream>>>(w_qkv, wqkvb, 786432 / 4);
  cvt_kernel<<<64, 256, 0, stream>>>(w_proj, wprojb, 262144 / 4);
  pbb_kernel<<<16, 256, 0, stream>>>(bias_table, rel_index, pbb);
  mbits_kernel<<<64, 64, 0, stream>>>(mask, mbits);

  // 392 m-tiles = 8 XCDs * 49; GEMM1: 6 n-tiles of 256, GEMM2: 2 n-tiles
  gemm_kernel<0, 6, 49><<<2352, 512, 131072, stream>>>(xbf, wqkvb, b_qkv, qkv, 1536);
  attn_kernel<<<8192, 256, 0, stream>>>(qkv, pbb, mbits, xbf);
  gemm_kernel<1, 2, 49><<<784, 512, 131072, stream>>>(xbf, wprojb, b_proj, d_out, 512);
}